// Round 7
// baseline (177.565 us; speedup 1.0000x reference)
//
#include <hip/hip_runtime.h>

#define BATCH 256
#define TT 256
#define DD 384
#define HH 64
#define SCALE 0.125f
#define SHIFT 14.0f

typedef __attribute__((ext_vector_type(8))) short short8;
typedef __attribute__((ext_vector_type(4))) short short4v;
typedef __attribute__((ext_vector_type(4))) float floatx4;

#define KS_STRIDE 72    // Ks [256][72] bf16
#define QS_STRIDE 72    // Qs [256][72] bf16
#define VT_STRIDE 264   // Vt [64][264] bf16
#define PS_STRIDE 40    // per-slot P scratch [16][40]
#define WELEMS (3 * DD * HH)   // 73,728 bf16 = 147,456 B packed W

__device__ __forceinline__ unsigned short f2bf(float f) {
    unsigned int u = __float_as_uint(f);
    u += 0x7fffu + ((u >> 16) & 1u);
    return (unsigned short)(u >> 16);
}
__device__ __forceinline__ float bf2f(unsigned short u) {
    return __uint_as_float(((unsigned int)u) << 16);
}

// async 16B global->LDS DMA; lane i lands at ldst + i*16B (ldst wave-uniform).
__device__ __forceinline__ void gld_lds16(const void* g, void* ldst) {
    __builtin_amdgcn_global_load_lds(
        (__attribute__((address_space(1))) void*)(unsigned long long)g,
        (__attribute__((address_space(3))) void*)(unsigned int)(unsigned long long)ldst,
        16, 0, 0);
}

// 8 fp32 -> bf16 A-fragment
__device__ __forceinline__ short8 cvt8(float4 f0, float4 f1) {
    short8 a;
    a[0] = (short)f2bf(f0.x); a[1] = (short)f2bf(f0.y);
    a[2] = (short)f2bf(f0.z); a[3] = (short)f2bf(f0.w);
    a[4] = (short)f2bf(f1.x); a[5] = (short)f2bf(f1.y);
    a[6] = (short)f2bf(f1.z); a[7] = (short)f2bf(f1.w);
    return a;
}

// Pack W fp32 [D][H] -> fragment-major bf16 (sector-packed k-bijection):
// wf[((ch*3+mat)*4+nt)*512 + lane*8 + j] = W[d][h],
//   d = 32ch + 4q + (j<4 ? j : j+12)  (q = lane>>4), h = 16nt + (lane&15).
// Shared by the A-side x loads, so the MFMA dot product is unchanged.
__global__ void pack_w_kernel(const float* __restrict__ wq,
                              const float* __restrict__ wk,
                              const float* __restrict__ wv,
                              unsigned short* __restrict__ wf) {
    int idx = blockIdx.x * 256 + threadIdx.x;
    if (idx >= WELEMS) return;
    int j = idx & 7;
    int lane = (idx >> 3) & 63;
    int nt = (idx >> 9) & 3;
    int rem = idx >> 11;                   // ch*3 + mat
    int mat = rem % 3;
    int ch = rem / 3;
    int l16 = lane & 15, q = lane >> 4;
    int h = 16 * nt + l16;
    int d = 32 * ch + 4 * q + (j < 4 ? j : j + 12);
    const float* w = (mat == 0) ? wq : (mat == 1) ? wk : wv;
    wf[idx] = f2bf(w[d * HH + h]);
}

// One block per batch, 256 thr = 4 waves = 1 wave/SIMD (full 512-VGPR budget).
// Each wave: M=64 rows in phase 1 (ILP replaces TLP); 4 q-groups in phase 2,
// processed as two interleaved pairs for in-order ILP.
__global__ __launch_bounds__(256, 1)
void fused_kernel(const float* __restrict__ x, const unsigned short* __restrict__ wfrag,
                  float* __restrict__ out) {
    __shared__ __align__(16) union LdsU {
        unsigned short w[WELEMS];                      // 147,456 B (phase 1)
        struct {
            unsigned short ks[TT * KS_STRIDE];         // 36,864 B
            unsigned short vt[HH * VT_STRIDE];         // 33,792 B
            unsigned short q[TT * QS_STRIDE];          // 36,864 B
            unsigned short p[8][16 * PS_STRIDE];       // 10,240 B (2 slots/wave)
        } s;
    } U;

    const int b = blockIdx.x;
    const int tid = threadIdx.x;
    const int wave = tid >> 6;     // 0..3
    const int lane = tid & 63;
    const int quad = lane >> 4;
    const int l16 = lane & 15;

    const float* xb = x + (size_t)b * TT * DD;

    // A-fragment rows: wave covers rows [64w, 64w+64), lane supplies rows
    // 64w + l16 + 16m (m=0..3); per chunk two 64B-contiguous wave reads.
    const float* xr0 = xb + (size_t)(64 * wave + l16) * DD + 4 * quad;
    const float* xr1 = xr0 + (size_t)16 * DD;
    const float* xr2 = xr0 + (size_t)32 * DD;
    const float* xr3 = xr0 + (size_t)48 * DD;

    // ---------------- Phase 1: Q,K,V = x_b @ {Wq,Wk,Wv} ----------------
    floatx4 cq[4][4] = {};
    floatx4 ck[4][4] = {};
    floatx4 cv[4][4] = {};

    // 3-chunk-deep x register pipeline: 3 bufs x 8 float4 = 96 VGPR.
    float4 xA_0, xA_1, xA_2, xA_3, xA_4, xA_5, xA_6, xA_7;
    float4 xB_0, xB_1, xB_2, xB_3, xB_4, xB_5, xB_6, xB_7;
    float4 xC_0, xC_1, xC_2, xC_3, xC_4, xC_5, xC_6, xC_7;

    #define XLOAD(B, CH)                                   \
        B##_0 = *(const float4*)(xr0 + (CH) * 32);         \
        B##_1 = *(const float4*)(xr0 + (CH) * 32 + 16);    \
        B##_2 = *(const float4*)(xr1 + (CH) * 32);         \
        B##_3 = *(const float4*)(xr1 + (CH) * 32 + 16);    \
        B##_4 = *(const float4*)(xr2 + (CH) * 32);         \
        B##_5 = *(const float4*)(xr2 + (CH) * 32 + 16);    \
        B##_6 = *(const float4*)(xr3 + (CH) * 32);         \
        B##_7 = *(const float4*)(xr3 + (CH) * 32 + 16);

    // Prefill chunks 0-2: x HBM stream starts before W staging.
    XLOAD(xA, 0)
    XLOAD(xB, 1)
    XLOAD(xC, 2)

    // Stage all packed W into LDS: 144 x 1KB granules, 36 per wave, linear,
    // conflict-free by construction (gld_lds16, no VALU, no ds_write).
    #pragma unroll
    for (int t = 0; t < 36; ++t) {
        int grp = wave * 36 + t;    // wave-uniform
        gld_lds16(wfrag + (size_t)grp * 512 + lane * 8, U.w + grp * 512);
    }

    __syncthreads();   // W staged (drains vmcnt; x chunks 0-2 also landed)

    // Per chunk: 4 A-frags, 12 W ds_read_b128 (each feeds 4 MFMAs), 48 MFMAs.
    // No barriers inside the sequence.
    #define GEMM_BODY(BUF, CH)                                                     \
        {                                                                          \
            short8 a0 = cvt8(BUF##_0, BUF##_1);                                    \
            short8 a1 = cvt8(BUF##_2, BUF##_3);                                    \
            short8 a2 = cvt8(BUF##_4, BUF##_5);                                    \
            short8 a3 = cvt8(BUF##_6, BUF##_7);                                    \
            if ((CH) + 3 < 12) { XLOAD(BUF, (CH) + 3) }                            \
            const unsigned short* wb = U.w + (size_t)(CH) * 12 * 512 + lane * 8;   \
            short8 wf_[12];                                                        \
            _Pragma("unroll")                                                      \
            for (int i = 0; i < 12; ++i)                                           \
                wf_[i] = *(const short8*)(wb + (size_t)i * 512);                   \
            _Pragma("unroll")                                                      \
            for (int nt = 0; nt < 4; ++nt) {                                       \
                cq[0][nt] = __builtin_amdgcn_mfma_f32_16x16x32_bf16(a0, wf_[nt], cq[0][nt], 0, 0, 0);      \
                cq[1][nt] = __builtin_amdgcn_mfma_f32_16x16x32_bf16(a1, wf_[nt], cq[1][nt], 0, 0, 0);      \
                cq[2][nt] = __builtin_amdgcn_mfma_f32_16x16x32_bf16(a2, wf_[nt], cq[2][nt], 0, 0, 0);      \
                cq[3][nt] = __builtin_amdgcn_mfma_f32_16x16x32_bf16(a3, wf_[nt], cq[3][nt], 0, 0, 0);      \
                ck[0][nt] = __builtin_amdgcn_mfma_f32_16x16x32_bf16(a0, wf_[4 + nt], ck[0][nt], 0, 0, 0);  \
                ck[1][nt] = __builtin_amdgcn_mfma_f32_16x16x32_bf16(a1, wf_[4 + nt], ck[1][nt], 0, 0, 0);  \
                ck[2][nt] = __builtin_amdgcn_mfma_f32_16x16x32_bf16(a2, wf_[4 + nt], ck[2][nt], 0, 0, 0);  \
                ck[3][nt] = __builtin_amdgcn_mfma_f32_16x16x32_bf16(a3, wf_[4 + nt], ck[3][nt], 0, 0, 0);  \
                cv[0][nt] = __builtin_amdgcn_mfma_f32_16x16x32_bf16(a0, wf_[8 + nt], cv[0][nt], 0, 0, 0);  \
                cv[1][nt] = __builtin_amdgcn_mfma_f32_16x16x32_bf16(a1, wf_[8 + nt], cv[1][nt], 0, 0, 0);  \
                cv[2][nt] = __builtin_amdgcn_mfma_f32_16x16x32_bf16(a2, wf_[8 + nt], cv[2][nt], 0, 0, 0);  \
                cv[3][nt] = __builtin_amdgcn_mfma_f32_16x16x32_bf16(a3, wf_[8 + nt], cv[3][nt], 0, 0, 0);  \
            }                                                                      \
        }

    GEMM_BODY(xA, 0)
    GEMM_BODY(xB, 1)
    GEMM_BODY(xC, 2)
    GEMM_BODY(xA, 3)
    GEMM_BODY(xB, 4)
    GEMM_BODY(xC, 5)
    GEMM_BODY(xA, 6)
    GEMM_BODY(xB, 7)
    GEMM_BODY(xC, 8)
    GEMM_BODY(xA, 9)
    GEMM_BODY(xB, 10)
    GEMM_BODY(xC, 11)
    #undef GEMM_BODY
    #undef XLOAD

    __syncthreads();   // all W-fragment reads done before overlaying with Q/Ks/Vt/P

    // C layout: row = 64*wave + 16*m + 4*quad + r, col = 16*nt + l16.
    // Vt written as short4 (consecutive rows) to quarter the ds_write count.
    #pragma unroll
    for (int m = 0; m < 4; ++m)
      #pragma unroll
      for (int nt = 0; nt < 4; ++nt) {
        int row0 = 64 * wave + 16 * m + 4 * quad;
        int col = 16 * nt + l16;
        #pragma unroll
        for (int r = 0; r < 4; ++r) {
            U.s.q[(row0 + r) * QS_STRIDE + col] = f2bf(cq[m][nt][r]);
            U.s.ks[(row0 + r) * KS_STRIDE + col] = f2bf(ck[m][nt][r]);
        }
        short4v v4;
        v4[0] = (short)f2bf(cv[m][nt][0]);
        v4[1] = (short)f2bf(cv[m][nt][1]);
        v4[2] = (short)f2bf(cv[m][nt][2]);
        v4[3] = (short)f2bf(cv[m][nt][3]);
        *(short4v*)(U.s.vt + (size_t)col * VT_STRIDE + row0) = v4;
      }

    __syncthreads();

    // ---------------- Phase 2: causal attention, fixed-shift softmax ----------------
    // Wave owns 4 groups in two pairs (gA small, gB large), each pair totals 9
    // key-chunks; A/B chains interleaved for in-order ILP. No barriers.
    float* outb = out + (size_t)b * TT * HH;
    unsigned short* psA = U.s.p[2 * wave];
    unsigned short* psB = U.s.p[2 * wave + 1];

    #pragma unroll 1
    for (int pass = 0; pass < 2; ++pass) {
        const int gA = pass ? (7 - wave) : wave;
        const int gB = pass ? (8 + wave) : (15 - wave);
        const int grA = 16 * gA, grB = 16 * gB;
        const int clA = gA >> 1, clB = gB >> 1;   // clB >= clA always

        short8 aqA0 = *(const short8*)(U.s.q + (size_t)(grA + l16) * QS_STRIDE + quad * 8);
        short8 aqA1 = *(const short8*)(U.s.q + (size_t)(grA + l16) * QS_STRIDE + 32 + quad * 8);
        short8 aqB0 = *(const short8*)(U.s.q + (size_t)(grB + l16) * QS_STRIDE + quad * 8);
        short8 aqB1 = *(const short8*)(U.s.q + (size_t)(grB + l16) * QS_STRIDE + 32 + quad * 8);

        floatx4 oA[4] = {}, oB[4] = {};
        float lA[4] = {0.f, 0.f, 0.f, 0.f};
        float lB[4] = {0.f, 0.f, 0.f, 0.f};

        for (int c = 0; c <= clB; ++c) {
            const bool doA = (c <= clA);
            floatx4 sA[2] = {}, sB[2] = {};
            #pragma unroll
            for (int ni = 0; ni < 2; ++ni) {
                const unsigned short* kbase =
                    U.s.ks + (size_t)(32 * c + 16 * ni + l16) * KS_STRIDE + quad * 8;
                sB[ni] = __builtin_amdgcn_mfma_f32_16x16x32_bf16(aqB0, *(const short8*)(kbase), sB[ni], 0, 0, 0);
                sB[ni] = __builtin_amdgcn_mfma_f32_16x16x32_bf16(aqB1, *(const short8*)(kbase + 32), sB[ni], 0, 0, 0);
            }
            if (doA) {
                #pragma unroll
                for (int ni = 0; ni < 2; ++ni) {
                    const unsigned short* kbase =
                        U.s.ks + (size_t)(32 * c + 16 * ni + l16) * KS_STRIDE + quad * 8;
                    sA[ni] = __builtin_amdgcn_mfma_f32_16x16x32_bf16(aqA0, *(const short8*)(kbase), sA[ni], 0, 0, 0);
                    sA[ni] = __builtin_amdgcn_mfma_f32_16x16x32_bf16(aqA1, *(const short8*)(kbase + 32), sA[ni], 0, 0, 0);
                }
            }
            {
                const bool partB = (c == clB);
                #pragma unroll
                for (int r = 0; r < 4; ++r) {
                    int row = grB + 4 * quad + r;
                    float p0 = __expf(sB[0][r] * SCALE - SHIFT);
                    float p1 = __expf(sB[1][r] * SCALE - SHIFT);
                    if (partB) {
                        if (32 * c + l16 > row) p0 = 0.f;
                        if (32 * c + 16 + l16 > row) p1 = 0.f;
                    }
                    unsigned short b0 = f2bf(p0), b1 = f2bf(p1);
                    lB[r] += bf2f(b0) + bf2f(b1);
                    psB[(4 * quad + r) * PS_STRIDE + l16] = b0;
                    psB[(4 * quad + r) * PS_STRIDE + 16 + l16] = b1;
                }
            }
            if (doA) {
                const bool partA = (c == clA);
                #pragma unroll
                for (int r = 0; r < 4; ++r) {
                    int row = grA + 4 * quad + r;
                    float p0 = __expf(sA[0][r] * SCALE - SHIFT);
                    float p1 = __expf(sA[1][r] * SCALE - SHIFT);
                    if (partA) {
                        if (32 * c + l16 > row) p0 = 0.f;
                        if (32 * c + 16 + l16 > row) p1 = 0.f;
                    }
                    unsigned short b0 = f2bf(p0), b1 = f2bf(p1);
                    lA[r] += bf2f(b0) + bf2f(b1);
                    psA[(4 * quad + r) * PS_STRIDE + l16] = b0;
                    psA[(4 * quad + r) * PS_STRIDE + 16 + l16] = b1;
                }
            }
            short8 apB = *(const short8*)(psB + l16 * PS_STRIDE + quad * 8);
            #pragma unroll
            for (int nt = 0; nt < 4; ++nt) {
                short8 bv = *(const short8*)(U.s.vt + (size_t)(16 * nt + l16) * VT_STRIDE + 32 * c + quad * 8);
                oB[nt] = __builtin_amdgcn_mfma_f32_16x16x32_bf16(apB, bv, oB[nt], 0, 0, 0);
            }
            if (doA) {
                short8 apA = *(const short8*)(psA + l16 * PS_STRIDE + quad * 8);
                #pragma unroll
                for (int nt = 0; nt < 4; ++nt) {
                    short8 bv = *(const short8*)(U.s.vt + (size_t)(16 * nt + l16) * VT_STRIDE + 32 * c + quad * 8);
                    oA[nt] = __builtin_amdgcn_mfma_f32_16x16x32_bf16(apA, bv, oA[nt], 0, 0, 0);
                }
            }
        }

        // Pass epilogue: l-reduction, one reciprocal per row, store both groups.
        float livA[4], livB[4];
        #pragma unroll
        for (int r = 0; r < 4; ++r) {
            float la = lA[r], lb = lB[r];
            la += __shfl_xor(la, 1); lb += __shfl_xor(lb, 1);
            la += __shfl_xor(la, 2); lb += __shfl_xor(lb, 2);
            la += __shfl_xor(la, 4); lb += __shfl_xor(lb, 4);
            la += __shfl_xor(la, 8); lb += __shfl_xor(lb, 8);
            livA[r] = 1.0f / la;
            livB[r] = 1.0f / lb;
        }
        #pragma unroll
        for (int nt = 0; nt < 4; ++nt)
          #pragma unroll
          for (int r = 0; r < 4; ++r) {
            int rowA = grA + 4 * quad + r;
            int rowB = grB + 4 * quad + r;
            outb[(size_t)rowA * HH + 16 * nt + l16] = oA[nt][r] * livA[r];
            outb[(size_t)rowB * HH + 16 * nt + l16] = oB[nt][r] * livB[r];
          }
    }
}

extern "C" void kernel_launch(void* const* d_in, const int* in_sizes, int n_in,
                              void* d_out, int out_size, void* d_ws, size_t ws_size,
                              hipStream_t stream) {
    const float* x  = (const float*)d_in[0];
    const float* wq = (const float*)d_in[1];
    const float* wk = (const float*)d_in[2];
    const float* wv = (const float*)d_in[3];
    unsigned short* wf = (unsigned short*)d_ws;   // fragment-major W, 147,456 B
    float* o = (float*)d_out;

    pack_w_kernel<<<(WELEMS + 255) / 256, 256, 0, stream>>>(wq, wk, wv, wf);
    fused_kernel<<<BATCH, 256, 0, stream>>>(x, wf, o);
}

// Round 8
// 167.596 us; speedup vs baseline: 1.0595x; 1.0595x over previous
//
#include <hip/hip_runtime.h>

#define BATCH 256
#define TT 256
#define DD 384
#define HH 64
#define SCALE 0.125f
#define SHIFT 14.0f

typedef __attribute__((ext_vector_type(8))) short short8;
typedef __attribute__((ext_vector_type(4))) float floatx4;

#define KS_STRIDE 72    // Ks [256][72] bf16
#define QS_STRIDE 72    // Qs [256][72] bf16
#define VT_STRIDE 264   // Vt [64][264] bf16
#define PS_STRIDE 40    // per-wave P scratch [16][40]
#define WELEMS (3 * DD * HH)   // 73,728 bf16 = 147,456 B packed W

__device__ __forceinline__ unsigned short f2bf(float f) {
    unsigned int u = __float_as_uint(f);
    u += 0x7fffu + ((u >> 16) & 1u);
    return (unsigned short)(u >> 16);
}
__device__ __forceinline__ float bf2f(unsigned short u) {
    return __uint_as_float(((unsigned int)u) << 16);
}

// HW packed bf16 convert: dst.lo = bf16(a), dst.hi = bf16(b), RNE — bit-identical
// to f2bf for finite values, 1 instruction instead of ~10.
__device__ __forceinline__ unsigned int cvtpk(float a, float b) {
    unsigned int r;
    asm("v_cvt_pk_bf16_f32 %0, %1, %2" : "=v"(r) : "v"(a), "v"(b));
    return r;
}

// async 16B global->LDS DMA; lane i lands at ldst + i*16B (ldst wave-uniform).
__device__ __forceinline__ void gld_lds16(const void* g, void* ldst) {
    __builtin_amdgcn_global_load_lds(
        (__attribute__((address_space(1))) void*)(unsigned long long)g,
        (__attribute__((address_space(3))) void*)(unsigned int)(unsigned long long)ldst,
        16, 0, 0);
}

// 8 fp32 -> bf16 A-fragment via 4 cvt_pk (was ~40 VALU ops)
__device__ __forceinline__ short8 cvt8(float4 f0, float4 f1) {
    union { unsigned int u[4]; short8 s; } r;
    r.u[0] = cvtpk(f0.x, f0.y);
    r.u[1] = cvtpk(f0.z, f0.w);
    r.u[2] = cvtpk(f1.x, f1.y);
    r.u[3] = cvtpk(f1.z, f1.w);
    return r.s;
}

// Pack W fp32 [D][H] -> fragment-major bf16 (sector-packed k-bijection):
// wf[((ch*3+mat)*4+nt)*512 + lane*8 + j] = W[d][h],
//   d = 32ch + 4q + (j<4 ? j : j+12)  (q = lane>>4), h = 16nt + (lane&15).
// Shared by the A-side x loads, so the MFMA dot product is unchanged.
__global__ void pack_w_kernel(const float* __restrict__ wq,
                              const float* __restrict__ wk,
                              const float* __restrict__ wv,
                              unsigned short* __restrict__ wf) {
    int idx = blockIdx.x * 256 + threadIdx.x;
    if (idx >= WELEMS) return;
    int j = idx & 7;
    int lane = (idx >> 3) & 63;
    int nt = (idx >> 9) & 3;
    int rem = idx >> 11;                   // ch*3 + mat
    int mat = rem % 3;
    int ch = rem / 3;
    int l16 = lane & 15, q = lane >> 4;
    int h = 16 * nt + l16;
    int d = 32 * ch + 4 * q + (j < 4 ? j : j + 12);
    const float* w = (mat == 0) ? wq : (mat == 1) ? wk : wv;
    wf[idx] = f2bf(w[d * HH + h]);
}

// One block per batch. 512 thr = 8 waves. LDS 147,456 B -> 1 block/CU.
__global__ __launch_bounds__(512, 2)
void fused_kernel(const float* __restrict__ x, const unsigned short* __restrict__ wfrag,
                  float* __restrict__ out) {
    __shared__ __align__(16) union LdsU {
        unsigned short w[WELEMS];                      // 147,456 B (phase 1)
        struct {
            unsigned short ks[TT * KS_STRIDE];         // 36,864 B
            unsigned short vt[HH * VT_STRIDE];         // 33,792 B
            unsigned short q[TT * QS_STRIDE];          // 36,864 B
            unsigned short p[8][16 * PS_STRIDE];       // 10,240 B
        } s;
    } U;

    const int b = blockIdx.x;
    const int tid = threadIdx.x;
    const int wave = tid >> 6;
    const int lane = tid & 63;
    const int quad = lane >> 4;
    const int l16 = lane & 15;

    const float* xb = x + (size_t)b * TT * DD;

    // Sector-packed A-fragment source: per chunk two 64B-contiguous wave reads.
    const float* xr0 = xb + (size_t)(32 * wave + l16) * DD + 4 * quad;
    const float* xr1 = xr0 + (size_t)16 * DD;

    // ---------------- Phase 1: Q,K,V = x_b @ {Wq,Wk,Wv} ----------------
    floatx4 cq[2][4] = {};
    floatx4 ck[2][4] = {};
    floatx4 cv[2][4] = {};

    // 4-chunk-deep x register pipeline.
    float4 xP0_0, xP0_1, xP0_2, xP0_3;
    float4 xP1_0, xP1_1, xP1_2, xP1_3;
    float4 xP2_0, xP2_1, xP2_2, xP2_3;
    float4 xP3_0, xP3_1, xP3_2, xP3_3;

    #define XLOAD(B, CH)                                   \
        B##_0 = *(const float4*)(xr0 + (CH) * 32);         \
        B##_1 = *(const float4*)(xr0 + (CH) * 32 + 16);    \
        B##_2 = *(const float4*)(xr1 + (CH) * 32);         \
        B##_3 = *(const float4*)(xr1 + (CH) * 32 + 16);

    XLOAD(xP0, 0)
    XLOAD(xP1, 1)
    XLOAD(xP2, 2)
    XLOAD(xP3, 3)

    // Stage all packed W into LDS: 144 x 1KB granules, 18 per wave, linear.
    #pragma unroll
    for (int t = 0; t < 18; ++t) {
        int grp = wave * 18 + t;    // wave-uniform
        gld_lds16(wfrag + (size_t)grp * 512 + lane * 8, U.w + grp * 512);
    }

    __syncthreads();   // W staged (drains vmcnt; x chunks 0-3 also landed)

    #define GEMM_BODY(B, CH)                                                       \
        {                                                                          \
            short8 a0 = cvt8(B##_0, B##_1);                                        \
            short8 a1 = cvt8(B##_2, B##_3);                                        \
            if ((CH) + 4 < 12) { XLOAD(B, (CH) + 4) }                              \
            const unsigned short* wb = U.w + (size_t)(CH) * 12 * 512 + lane * 8;   \
            short8 wf_[12];                                                        \
            _Pragma("unroll")                                                      \
            for (int i = 0; i < 12; ++i)                                           \
                wf_[i] = *(const short8*)(wb + (size_t)i * 512);                   \
            _Pragma("unroll")                                                      \
            for (int nt = 0; nt < 4; ++nt) {                                       \
                cq[0][nt] = __builtin_amdgcn_mfma_f32_16x16x32_bf16(a0, wf_[nt], cq[0][nt], 0, 0, 0);      \
                cq[1][nt] = __builtin_amdgcn_mfma_f32_16x16x32_bf16(a1, wf_[nt], cq[1][nt], 0, 0, 0);      \
                ck[0][nt] = __builtin_amdgcn_mfma_f32_16x16x32_bf16(a0, wf_[4 + nt], ck[0][nt], 0, 0, 0);  \
                ck[1][nt] = __builtin_amdgcn_mfma_f32_16x16x32_bf16(a1, wf_[4 + nt], ck[1][nt], 0, 0, 0);  \
                cv[0][nt] = __builtin_amdgcn_mfma_f32_16x16x32_bf16(a0, wf_[8 + nt], cv[0][nt], 0, 0, 0);  \
                cv[1][nt] = __builtin_amdgcn_mfma_f32_16x16x32_bf16(a1, wf_[8 + nt], cv[1][nt], 0, 0, 0);  \
            }                                                                      \
        }

    GEMM_BODY(xP0, 0)
    GEMM_BODY(xP1, 1)
    GEMM_BODY(xP2, 2)
    GEMM_BODY(xP3, 3)
    GEMM_BODY(xP0, 4)
    GEMM_BODY(xP1, 5)
    GEMM_BODY(xP2, 6)
    GEMM_BODY(xP3, 7)
    GEMM_BODY(xP0, 8)
    GEMM_BODY(xP1, 9)
    GEMM_BODY(xP2, 10)
    GEMM_BODY(xP3, 11)
    #undef GEMM_BODY
    #undef XLOAD

    __syncthreads();   // all W-fragment reads done before overlaying with Q/Ks/Vt/P

    // C layout: row = 32*wave + 16*mi + 4*quad + r, col = 16*nt + l16
    #pragma unroll
    for (int mi = 0; mi < 2; ++mi)
      #pragma unroll
      for (int nt = 0; nt < 4; ++nt)
        #pragma unroll
        for (int r = 0; r < 4; ++r) {
            int row = 32 * wave + 16 * mi + 4 * quad + r;
            int col = 16 * nt + l16;
            U.s.q[row * QS_STRIDE + col] = f2bf(cq[mi][nt][r]);
            U.s.ks[row * KS_STRIDE + col] = f2bf(ck[mi][nt][r]);
            U.s.vt[col * VT_STRIDE + row] = f2bf(cv[mi][nt][r]);
        }

    __syncthreads();

    // ---------------- Phase 2: causal attention, fixed-shift softmax ----------------
    // wave handles row-groups g = wave and g = 15-wave (9 key-chunks, balanced).
    // K/V fragments prefetched one chunk ahead into registers: the serial chain
    // per chunk is QK(regs) -> exp/pack -> P LDS roundtrip -> PV(regs).
    floatx4 o[2][4] = {};
    float l_run[2][4] = {{0.f, 0.f, 0.f, 0.f}, {0.f, 0.f, 0.f, 0.f}};
    unsigned short* psw = U.s.p[wave];

    #pragma unroll
    for (int gi = 0; gi < 2; ++gi) {
        int g = gi ? (15 - wave) : wave;
        int gr0 = 16 * g;
        short8 aq0 = *(const short8*)(U.s.q + (size_t)(gr0 + l16) * QS_STRIDE + quad * 8);
        short8 aq1 = *(const short8*)(U.s.q + (size_t)(gr0 + l16) * QS_STRIDE + 32 + quad * 8);
        int clast = g >> 1;

        short8 kf[4], vf[4], kn[4], vn[4];

        #define LOADKV(KD, VD, C)                                                          \
            {                                                                              \
                _Pragma("unroll")                                                          \
                for (int ni = 0; ni < 2; ++ni) {                                           \
                    const unsigned short* kb =                                             \
                        U.s.ks + (size_t)(32 * (C) + 16 * ni + l16) * KS_STRIDE + quad * 8;\
                    KD[2 * ni]     = *(const short8*)(kb);                                 \
                    KD[2 * ni + 1] = *(const short8*)(kb + 32);                            \
                }                                                                          \
                _Pragma("unroll")                                                          \
                for (int nt = 0; nt < 4; ++nt)                                             \
                    VD[nt] = *(const short8*)(U.s.vt + (size_t)(16 * nt + l16) * VT_STRIDE \
                                              + 32 * (C) + quad * 8);                      \
            }

        LOADKV(kf, vf, 0)

        for (int c = 0; c <= clast; ++c) {
            if (c < clast) { LOADKV(kn, vn, c + 1) }     // in-flight during QK/SM/PV
            floatx4 s[2] = {};
            __builtin_amdgcn_s_setprio(1);
            s[0] = __builtin_amdgcn_mfma_f32_16x16x32_bf16(aq0, kf[0], s[0], 0, 0, 0);
            s[0] = __builtin_amdgcn_mfma_f32_16x16x32_bf16(aq1, kf[1], s[0], 0, 0, 0);
            s[1] = __builtin_amdgcn_mfma_f32_16x16x32_bf16(aq0, kf[2], s[1], 0, 0, 0);
            s[1] = __builtin_amdgcn_mfma_f32_16x16x32_bf16(aq1, kf[3], s[1], 0, 0, 0);
            __builtin_amdgcn_s_setprio(0);
            bool partial = (c == clast);
            #pragma unroll
            for (int r = 0; r < 4; ++r) {
                int row = gr0 + 4 * quad + r;
                float p0 = __expf(s[0][r] * SCALE - SHIFT);
                float p1 = __expf(s[1][r] * SCALE - SHIFT);
                if (partial) {
                    if (32 * c + l16 > row) p0 = 0.f;
                    if (32 * c + 16 + l16 > row) p1 = 0.f;
                }
                unsigned int pk = cvtpk(p0, p1);
                unsigned short b0 = (unsigned short)pk;
                unsigned short b1 = (unsigned short)(pk >> 16);
                l_run[gi][r] += bf2f(b0) + bf2f(b1);   // consistent with bf16 P fed to PV
                psw[(4 * quad + r) * PS_STRIDE + l16] = b0;
                psw[(4 * quad + r) * PS_STRIDE + 16 + l16] = b1;
            }
            short8 ap = *(const short8*)(psw + l16 * PS_STRIDE + quad * 8);
            __builtin_amdgcn_s_setprio(1);
            #pragma unroll
            for (int nt = 0; nt < 4; ++nt)
                o[gi][nt] = __builtin_amdgcn_mfma_f32_16x16x32_bf16(ap, vf[nt], o[gi][nt], 0, 0, 0);
            __builtin_amdgcn_s_setprio(0);
            if (c < clast) {
                #pragma unroll
                for (int i = 0; i < 4; ++i) { kf[i] = kn[i]; vf[i] = vn[i]; }
            }
        }
        #undef LOADKV
    }

    // ---------------- Epilogue: l-reduction, one reciprocal per row, store ----------------
    float* outb = out + (size_t)b * TT * HH;
    #pragma unroll
    for (int gi = 0; gi < 2; ++gi) {
        int g = gi ? (15 - wave) : wave;
        float linv[4];
        #pragma unroll
        for (int r = 0; r < 4; ++r) {
            float l = l_run[gi][r];
            l += __shfl_xor(l, 1);
            l += __shfl_xor(l, 2);
            l += __shfl_xor(l, 4);
            l += __shfl_xor(l, 8);
            linv[r] = 1.0f / l;
        }
        #pragma unroll
        for (int nt = 0; nt < 4; ++nt)
          #pragma unroll
          for (int r = 0; r < 4; ++r) {
            int row = 16 * g + 4 * quad + r;
            outb[(size_t)row * HH + 16 * nt + l16] = o[gi][nt][r] * linv[r];
          }
    }
}

extern "C" void kernel_launch(void* const* d_in, const int* in_sizes, int n_in,
                              void* d_out, int out_size, void* d_ws, size_t ws_size,
                              hipStream_t stream) {
    const float* x  = (const float*)d_in[0];
    const float* wq = (const float*)d_in[1];
    const float* wk = (const float*)d_in[2];
    const float* wv = (const float*)d_in[3];
    unsigned short* wf = (unsigned short*)d_ws;   // fragment-major W, 147,456 B
    float* o = (float*)d_out;

    pack_w_kernel<<<(WELEMS + 255) / 256, 256, 0, stream>>>(wq, wk, wv, wf);
    fused_kernel<<<BATCH, 512, 0, stream>>>(x, wf, o);
}